// Round 4
// baseline (7247.117 us; speedup 1.0000x reference)
//
#include <hip/hip_runtime.h>
#include <math.h>

#define S_LEN   2048
#define HIDDEN  4096
#define N_HEADS 32
#define N_KV    8
#define HEAD_DIM 128
#define NCAND   1844      // S - RECENT
#define HEAVY_K 819
#define MASK_LEN 2049     // S + 1

using bf16x8 = __attribute__((ext_vector_type(8))) short;
using f32x4  = __attribute__((ext_vector_type(4))) float;

__device__ inline unsigned short f2bf(float x) {
  unsigned u = __builtin_bit_cast(unsigned, x);
  unsigned r = (u + 0x7FFFu + ((u >> 16) & 1u)) >> 16;
  return (unsigned short)r;
}

// ---------------------------------------------------------------------------
// f32 GEMM, 128x128 tile, BK=32, 8x8 micro-tile.  Mask-critical (Wq/Wk).
// Per-element accumulation is strictly k-ascending -> bit-identical results
// to the previous 64-tile version (mask provably unchanged).
// As stored k-major [kk][m] stride 132 (free frag reads); Bs stride 129
// (2-way max on reads = free; 4-way only on the rare staging stores).
// ---------------------------------------------------------------------------
__global__ __launch_bounds__(256, 3) void gemm_f32_big(
    const float* __restrict__ A, const float* __restrict__ B,
    float* __restrict__ C, int M, int N, int K)
{
  __shared__ float As[32][132];
  __shared__ float Bs[32][129];
  const int t  = threadIdx.x;
  const int tx = t & 15;
  const int ty = t >> 4;
  const int bm = blockIdx.y << 7;
  const int bn = blockIdx.x << 7;
  const int am  = t >> 3;        // 0..31 (+p*32): A row (m)
  const int ac4 = t & 7;         // float4 index along k
  const int brow = t >> 5;       // 0..7 (+p*8): B k-row
  const int bc4  = t & 31;       // float4 index along n
  const float4* A4 = (const float4*)A;
  const float4* B4 = (const float4*)B;
  const int K4 = K >> 2;
  const int N4 = N >> 2;

  float acc[8][8];
#pragma unroll
  for (int i = 0; i < 8; i++)
#pragma unroll
    for (int j = 0; j < 8; j++) acc[i][j] = 0.f;

  for (int k0 = 0; k0 < K; k0 += 32) {
    float4 areg[4], breg[4];
#pragma unroll
    for (int p = 0; p < 4; p++) {
      areg[p] = A4[(size_t)(bm + am + p * 32) * K4 + (k0 >> 2) + ac4];
      breg[p] = B4[(size_t)(k0 + brow + p * 8) * N4 + (bn >> 2) + bc4];
    }
    __syncthreads();
#pragma unroll
    for (int p = 0; p < 4; p++) {
      int m = am + p * 32;
      As[ac4 * 4 + 0][m] = areg[p].x;
      As[ac4 * 4 + 1][m] = areg[p].y;
      As[ac4 * 4 + 2][m] = areg[p].z;
      As[ac4 * 4 + 3][m] = areg[p].w;
      *(float4*)&Bs[brow + p * 8][bc4 * 4] = breg[p];
    }
    __syncthreads();
#pragma unroll
    for (int kk = 0; kk < 32; kk++) {
      float4 a0 = *(const float4*)&As[kk][ty * 8];
      float4 a1 = *(const float4*)&As[kk][ty * 8 + 4];
      float4 b0 = *(const float4*)&Bs[kk][tx * 8];
      float4 b1 = *(const float4*)&Bs[kk][tx * 8 + 4];
      float av[8] = {a0.x, a0.y, a0.z, a0.w, a1.x, a1.y, a1.z, a1.w};
      float bv[8] = {b0.x, b0.y, b0.z, b0.w, b1.x, b1.y, b1.z, b1.w};
#pragma unroll
      for (int i = 0; i < 8; i++)
#pragma unroll
        for (int j = 0; j < 8; j++) acc[i][j] += av[i] * bv[j];
    }
  }

#pragma unroll
  for (int i = 0; i < 8; i++) {
    float4 o0, o1;
    o0.x = acc[i][0]; o0.y = acc[i][1]; o0.z = acc[i][2]; o0.w = acc[i][3];
    o1.x = acc[i][4]; o1.y = acc[i][5]; o1.z = acc[i][6]; o1.w = acc[i][7];
    float* crow = &C[(size_t)(bm + ty * 8 + i) * N + bn + tx * 8];
    *(float4*)crow = o0;
    *(float4*)(crow + 4) = o1;
  }
}

// ---------------------------------------------------------------------------
// bf16 MFMA GEMM: C(f32)[M,N] = A(bf16)[M,K] * BT(bf16)[N,K]^T.
// Tile 64x64, BK=32, 4 waves x 2x2 mfma_f32_16x16x32_bf16.
// ---------------------------------------------------------------------------
__global__ __launch_bounds__(256) void gemm_bf16(
    const unsigned short* __restrict__ A, const unsigned short* __restrict__ BT,
    float* __restrict__ C, int M, int N, int K)
{
  __shared__ unsigned short As[64 * 40];
  __shared__ unsigned short Bs[64 * 40];
  const int t    = threadIdx.x;
  const int lane = t & 63;
  const int wave = t >> 6;
  const int mbase = (wave >> 1) * 32;
  const int nbase = (wave & 1) * 32;
  const int bm = blockIdx.y << 6;
  const int bn = blockIdx.x << 6;
  const int srow = t >> 2;
  const int scol = (t & 3) * 8;
  const int l16 = lane & 15;
  const int lk  = (lane >> 4) * 8;

  f32x4 acc00 = {0.f,0.f,0.f,0.f}, acc01 = {0.f,0.f,0.f,0.f};
  f32x4 acc10 = {0.f,0.f,0.f,0.f}, acc11 = {0.f,0.f,0.f,0.f};

  for (int k0 = 0; k0 < K; k0 += 32) {
    float4 av = *(const float4*)(A  + (size_t)(bm + srow) * K + k0 + scol);
    float4 bv = *(const float4*)(BT + (size_t)(bn + srow) * K + k0 + scol);
    __syncthreads();
    *(float4*)(As + srow * 40 + scol) = av;
    *(float4*)(Bs + srow * 40 + scol) = bv;
    __syncthreads();
    bf16x8 a0 = *(const bf16x8*)(As + (mbase + l16)      * 40 + lk);
    bf16x8 a1 = *(const bf16x8*)(As + (mbase + 16 + l16) * 40 + lk);
    bf16x8 b0 = *(const bf16x8*)(Bs + (nbase + l16)      * 40 + lk);
    bf16x8 b1 = *(const bf16x8*)(Bs + (nbase + 16 + l16) * 40 + lk);
    acc00 = __builtin_amdgcn_mfma_f32_16x16x32_bf16(a0, b0, acc00, 0, 0, 0);
    acc01 = __builtin_amdgcn_mfma_f32_16x16x32_bf16(a0, b1, acc01, 0, 0, 0);
    acc10 = __builtin_amdgcn_mfma_f32_16x16x32_bf16(a1, b0, acc10, 0, 0, 0);
    acc11 = __builtin_amdgcn_mfma_f32_16x16x32_bf16(a1, b1, acc11, 0, 0, 0);
  }

  const int rr = (lane >> 4) * 4;
#pragma unroll
  for (int r = 0; r < 4; r++) {
    C[(size_t)(bm + mbase +      rr + r) * N + bn + nbase +      l16] = acc00[r];
    C[(size_t)(bm + mbase +      rr + r) * N + bn + nbase + 16 + l16] = acc01[r];
    C[(size_t)(bm + mbase + 16 + rr + r) * N + bn + nbase +      l16] = acc10[r];
    C[(size_t)(bm + mbase + 16 + rr + r) * N + bn + nbase + 16 + l16] = acc11[r];
  }
}

// ---------------------------------------------------------------------------
// f32 -> bf16 row-major convert.
// ---------------------------------------------------------------------------
__global__ __launch_bounds__(256) void conv_rm(
    const float* __restrict__ src, unsigned short* __restrict__ dst, int n4)
{
  int i = blockIdx.x * 256 + threadIdx.x;
  if (i >= n4) return;
  float4 v = ((const float4*)src)[i];
  ushort4 o;
  o.x = f2bf(v.x); o.y = f2bf(v.y); o.z = f2bf(v.z); o.w = f2bf(v.w);
  ((ushort4*)dst)[i] = o;
}

// ---------------------------------------------------------------------------
// f32 [K][N] -> bf16 [N][K] transpose-convert, 32x32 tiles through LDS.
// ---------------------------------------------------------------------------
__global__ __launch_bounds__(256) void conv_T(
    const float* __restrict__ src, unsigned short* __restrict__ dst,
    int K, int N)
{
  __shared__ float tile[32][33];
  const int tj = blockIdx.x;   // N tile
  const int ti = blockIdx.y;   // K tile
  const int t = threadIdx.x;
  for (int idx = t; idx < 1024; idx += 256) {
    int r = idx >> 5, c = idx & 31;
    tile[r][c] = src[(size_t)(ti * 32 + r) * N + tj * 32 + c];
  }
  __syncthreads();
  for (int idx = t; idx < 1024; idx += 256) {
    int r = idx >> 5, c = idx & 31;
    dst[(size_t)(tj * 32 + r) * K + ti * 32 + c] = f2bf(tile[c][r]);
  }
}

// ---------------------------------------------------------------------------
// In-place RoPE.  inv_freq via f64 pow then rounded to f32 (matches numpy).
// ---------------------------------------------------------------------------
__global__ __launch_bounds__(256) void rope_kernel(
    float* __restrict__ buf, const int* __restrict__ pos_ids, int ncols)
{
  __shared__ float invf_s[64];
  if (threadIdx.x < 64)
    invf_s[threadIdx.x] =
        (float)(1.0 / pow(10000.0, (double)threadIdx.x * (1.0 / 64.0)));
  __syncthreads();

  int i = blockIdx.x * 256 + threadIdx.x;
  int half = ncols >> 1;
  int total = S_LEN * half;
  if (i >= total) return;
  int row = i / half;
  int rem = i - row * half;
  int hh = rem >> 6;
  int d  = rem & 63;
  float p = (float)pos_ids[row];
  float ang = p * invf_s[d];
  float c = cosf(ang);
  float s = sinf(ang);
  float* base = buf + (size_t)row * ncols + hh * HEAD_DIM;
  float x0 = base[d];
  float x1 = base[d + 64];
  base[d]      = x0 * c - x1 * s;
  base[d + 64] = x1 * c + x0 * s;
}

// ---------------------------------------------------------------------------
// Attention pass 1: softmax denominator only (max-free; |s*SCALE| <~ 15).
// ---------------------------------------------------------------------------
__global__ __launch_bounds__(256, 4) void attn_pass1(
    const float* __restrict__ Qr, const float* __restrict__ Kr,
    float* __restrict__ Lrow)
{
  const int qt = gridDim.x - 1 - blockIdx.x;   // big blocks first
  const int h  = blockIdx.y;
  const int q0 = qt << 5;
  const int kvh = h >> 2;
  __shared__ float Qs[32 * 132];
  __shared__ float Ks[32 * 132];
  const int t  = threadIdx.x;
  const int tx = t & 15;
  const int ty = t >> 4;
  const float SCALE = 1.0f / sqrtf(128.0f);

  for (int i = t; i < 32 * 32; i += 256) {
    int r = i >> 5, c4 = i & 31;
    float4 v = ((const float4*)Qr)[(size_t)(q0 + r) * (HIDDEN / 4) + h * 32 + c4];
    *(float4*)(Qs + r * 132 + c4 * 4) = v;
  }

  const int r0 = ty, r1 = ty + 16;
  float l0 = 0.f, l1 = 0.f;

  for (int kt = 0; kt <= qt; kt++) {
    const int k0 = kt << 5;
    __syncthreads();
    for (int i = t; i < 32 * 32; i += 256) {
      int r = i >> 5, c4 = i & 31;
      float4 v = ((const float4*)Kr)[(size_t)(k0 + r) * (N_KV * HEAD_DIM / 4) + kvh * 32 + c4];
      *(float4*)(Ks + r * 132 + c4 * 4) = v;
    }
    __syncthreads();

    float s00 = 0.f, s01 = 0.f, s10 = 0.f, s11 = 0.f;
    const float* qa = Qs + r0 * 132;
    const float* qb = Qs + r1 * 132;
    const float* ka = Ks + tx * 132;
    const float* kb = Ks + (tx + 16) * 132;
#pragma unroll
    for (int kk = 0; kk < 128; kk += 4) {
      float4 a0 = *(const float4*)(qa + kk);
      float4 a1 = *(const float4*)(qb + kk);
      float4 b0 = *(const float4*)(ka + kk);
      float4 b1 = *(const float4*)(kb + kk);
      s00 += a0.x*b0.x + a0.y*b0.y + a0.z*b0.z + a0.w*b0.w;
      s01 += a0.x*b1.x + a0.y*b1.y + a0.z*b1.z + a0.w*b1.w;
      s10 += a1.x*b0.x + a1.y*b0.y + a1.z*b0.z + a1.w*b0.w;
      s11 += a1.x*b1.x + a1.y*b1.y + a1.z*b1.z + a1.w*b1.w;
    }
    l0 += (k0 + tx      <= q0 + r0) ? expf(s00 * SCALE) : 0.f;
    l0 += (k0 + tx + 16 <= q0 + r0) ? expf(s01 * SCALE) : 0.f;
    l1 += (k0 + tx      <= q0 + r1) ? expf(s10 * SCALE) : 0.f;
    l1 += (k0 + tx + 16 <= q0 + r1) ? expf(s11 * SCALE) : 0.f;
  }

#pragma unroll
  for (int off = 1; off < 16; off <<= 1) {
    l0 += __shfl_xor(l0, off);
    l1 += __shfl_xor(l1, off);
  }
  if (tx == 0) {
    Lrow[h * S_LEN + q0 + r0] = l0;
    Lrow[h * S_LEN + q0 + r1] = l1;
  }
}

// ---------------------------------------------------------------------------
// Attention pass 2.  Qs stride 130 floats: b128 phases interleave lanes, so
// stride must be !=0 mod 32 banks for the ty-dependent Q frag reads; 130
// (==2 mod 32) gives max 2-way aliasing (free, m136) AND keeps LDS at
// 54144B -> 54272 rounded -> 3 blocks/CU.  (128 caused 70M conflicts.)
// ---------------------------------------------------------------------------
__global__ __launch_bounds__(256, 4) void attn_pass2(
    const float* __restrict__ Qr, const float* __restrict__ Kr,
    const float* __restrict__ Vr, const float* __restrict__ Lrow,
    float* __restrict__ cs, unsigned short* __restrict__ attnb)
{
  const int qt = gridDim.x - 1 - blockIdx.x;   // big blocks first
  const int h  = blockIdx.y;
  const int q0 = qt << 5;
  const int kvh = h >> 2;
  __shared__ float Qs[32 * 130];
  __shared__ float Ks[32 * 132];
  __shared__ float Vs[32 * 128];
  __shared__ float Ps[32 * 33];
  const int t  = threadIdx.x;
  const int tx = t & 15;
  const int ty = t >> 4;
  const float SCALE = 1.0f / sqrtf(128.0f);

  for (int i = t; i < 32 * 32; i += 256) {
    int r = i >> 5, c4 = i & 31;
    float4 v = ((const float4*)Qr)[(size_t)(q0 + r) * (HIDDEN / 4) + h * 32 + c4];
    *(float4*)(Qs + r * 130 + c4 * 4) = v;
  }

  const int r0 = ty, r1 = ty + 16;
  const float iA = 1.0f / Lrow[h * S_LEN + q0 + r0];
  const float iB = 1.0f / Lrow[h * S_LEN + q0 + r1];

  float4 o00 = {0,0,0,0}, o01 = {0,0,0,0}, o10 = {0,0,0,0}, o11 = {0,0,0,0};

  for (int kt = 0; kt <= qt; kt++) {
    const int k0 = kt << 5;
    __syncthreads();
    for (int i = t; i < 32 * 32; i += 256) {
      int r = i >> 5, c4 = i & 31;
      size_t g = (size_t)(k0 + r) * (N_KV * HEAD_DIM / 4) + kvh * 32 + c4;
      *(float4*)(Ks + r * 132 + c4 * 4) = ((const float4*)Kr)[g];
      *(float4*)(Vs + r * 128 + c4 * 4) = ((const float4*)Vr)[g];
    }
    __syncthreads();

    float s00 = 0.f, s01 = 0.f, s10 = 0.f, s11 = 0.f;
    const float* qa = Qs + r0 * 130;
    const float* qb = Qs + r1 * 130;
    const float* ka = Ks + tx * 132;
    const float* kb = Ks + (tx + 16) * 132;
#pragma unroll
    for (int kk = 0; kk < 128; kk += 4) {
      float4 a0 = *(const float4*)(qa + kk);
      float4 a1 = *(const float4*)(qb + kk);
      float4 b0 = *(const float4*)(ka + kk);
      float4 b1 = *(const float4*)(kb + kk);
      s00 += a0.x*b0.x + a0.y*b0.y + a0.z*b0.z + a0.w*b0.w;
      s01 += a0.x*b1.x + a0.y*b1.y + a0.z*b1.z + a0.w*b1.w;
      s10 += a1.x*b0.x + a1.y*b0.y + a1.z*b0.z + a1.w*b0.w;
      s11 += a1.x*b1.x + a1.y*b1.y + a1.z*b1.z + a1.w*b1.w;
    }

    float w00 = (k0 + tx      <= q0 + r0) ? expf(s00 * SCALE) * iA : 0.f;
    float w01 = (k0 + tx + 16 <= q0 + r0) ? expf(s01 * SCALE) * iA : 0.f;
    float w10 = (k0 + tx      <= q0 + r1) ? expf(s10 * SCALE) * iB : 0.f;
    float w11 = (k0 + tx + 16 <= q0 + r1) ? expf(s11 * SCALE) * iB : 0.f;
    Ps[r0 * 33 + tx]      = w00;
    Ps[r0 * 33 + tx + 16] = w01;
    Ps[r1 * 33 + tx]      = w10;
    Ps[r1 * 33 + tx + 16] = w11;
    __syncthreads();

    if (t < 32) {
      float sum = 0.f;
#pragma unroll
      for (int r = 0; r < 32; r++) sum += Ps[r * 33 + t];
      atomicAdd(&cs[h * S_LEN + k0 + t], sum);
    }

#pragma unroll 8
    for (int c = 0; c < 32; c++) {
      float w0 = Ps[r0 * 33 + c];
      float w1 = Ps[r1 * 33 + c];
      float4 va = *(const float4*)(Vs + c * 128 + tx * 4);
      float4 vb = *(const float4*)(Vs + c * 128 + 64 + tx * 4);
      o00.x += w0*va.x; o00.y += w0*va.y; o00.z += w0*va.z; o00.w += w0*va.w;
      o01.x += w0*vb.x; o01.y += w0*vb.y; o01.z += w0*vb.z; o01.w += w0*vb.w;
      o10.x += w1*va.x; o10.y += w1*va.y; o10.z += w1*va.z; o10.w += w1*va.w;
      o11.x += w1*vb.x; o11.y += w1*vb.y; o11.z += w1*vb.z; o11.w += w1*vb.w;
    }
  }

  unsigned short* ob0 = attnb + (size_t)(q0 + r0) * HIDDEN + h * HEAD_DIM;
  unsigned short* ob1 = attnb + (size_t)(q0 + r1) * HIDDEN + h * HEAD_DIM;
  ushort4 p;
  p.x = f2bf(o00.x); p.y = f2bf(o00.y); p.z = f2bf(o00.z); p.w = f2bf(o00.w);
  *(ushort4*)(ob0 + tx * 4) = p;
  p.x = f2bf(o01.x); p.y = f2bf(o01.y); p.z = f2bf(o01.z); p.w = f2bf(o01.w);
  *(ushort4*)(ob0 + 64 + tx * 4) = p;
  p.x = f2bf(o10.x); p.y = f2bf(o10.y); p.z = f2bf(o10.z); p.w = f2bf(o10.w);
  *(ushort4*)(ob1 + tx * 4) = p;
  p.x = f2bf(o11.x); p.y = f2bf(o11.y); p.z = f2bf(o11.z); p.w = f2bf(o11.w);
  *(ushort4*)(ob1 + 64 + tx * 4) = p;
}

// ---------------------------------------------------------------------------
// Exact top-HEAVY_K of the first NCAND scores per head via O(n^2) ranking.
// ---------------------------------------------------------------------------
__global__ __launch_bounds__(256) void topk_mask_kernel(
    const float* __restrict__ cs, float* __restrict__ maskout)
{
  const int h = blockIdx.x;
  __shared__ float sv[NCAND];
  const float* s = cs + h * S_LEN;
  const int t = threadIdx.x;
  for (int i = t; i < NCAND; i += 256) sv[i] = s[i];
  __syncthreads();

  float v[8];
  int cnt[8];
#pragma unroll
  for (int j = 0; j < 8; j++) {
    int i = t + j * 256;
    v[j] = (i < NCAND) ? sv[i] : INFINITY;
    cnt[j] = 0;
  }
  for (int jj = 0; jj < NCAND; jj++) {
    float x = sv[jj];
#pragma unroll
    for (int j = 0; j < 8; j++) {
      int i = t + j * 256;
      cnt[j] += ((x > v[j]) || (x == v[j] && jj < i)) ? 1 : 0;
    }
  }

  float* mrow = maskout + h * MASK_LEN;
  for (int i = t; i < MASK_LEN; i += 256)
    mrow[i] = (i >= NCAND + 1) ? 1.0f : 0.0f;
#pragma unroll
  for (int j = 0; j < 8; j++) {
    int i = t + j * 256;
    if (i < NCAND && cnt[j] < HEAVY_K) mrow[i] = 1.0f;
  }
}

__global__ __launch_bounds__(256) void zero_kernel(float* __restrict__ p, int n)
{
  int i = blockIdx.x * 256 + threadIdx.x;
  if (i < n) p[i] = 0.f;
}

// ---------------------------------------------------------------------------
extern "C" void kernel_launch(void* const* d_in, const int* in_sizes, int n_in,
                              void* d_out, int out_size, void* d_ws, size_t ws_size,
                              hipStream_t stream)
{
  (void)in_sizes; (void)n_in; (void)out_size; (void)ws_size;
  const float* hs = (const float*)d_in[0];
  const int*  pos = (const int*)d_in[1];
  const float* Wq = (const float*)d_in[2];
  const float* Wk = (const float*)d_in[3];
  const float* Wv = (const float*)d_in[4];
  const float* Wo = (const float*)d_in[5];
  float* out = (float*)d_out;

  // workspace layout (~104.5 MB)
  char* w = (char*)d_ws;
  float* Qraw          = (float*)(w);                       // 32 MB
  float* Kraw          = (float*)(w + 33554432);            //  8 MB
  float* Vraw          = (float*)(w + 41943040);            //  8 MB
  float* Lrow          = (float*)(w + 50331648);            //  0.25 MB
  float* cs            = (float*)(w + 50593792);            //  0.25 MB
  unsigned short* WoT  = (unsigned short*)(w + 50855936);   // 32 MB
  unsigned short* WvT  = (unsigned short*)(w + 84410368);   //  8 MB
  unsigned short* hsb  = (unsigned short*)(w + 92798976);   // 16 MB
  unsigned short* attnb = hsb;  // overlay: hsb dead after Wv gemm

  dim3 blk(256);

  conv_rm<<<(S_LEN * HIDDEN / 4 + 255) / 256, blk, 0, stream>>>(
      hs, hsb, S_LEN * HIDDEN / 4);
  conv_T<<<dim3((N_KV * HEAD_DIM) / 32, HIDDEN / 32), blk, 0, stream>>>(
      Wv, WvT, HIDDEN, N_KV * HEAD_DIM);
  conv_T<<<dim3(HIDDEN / 32, HIDDEN / 32), blk, 0, stream>>>(
      Wo, WoT, HIDDEN, HIDDEN);

  gemm_f32_big<<<dim3(HIDDEN / 128, S_LEN / 128), blk, 0, stream>>>(
      hs, Wq, Qraw, S_LEN, HIDDEN, HIDDEN);
  gemm_f32_big<<<dim3((N_KV * HEAD_DIM) / 128, S_LEN / 128), blk, 0, stream>>>(
      hs, Wk, Kraw, S_LEN, N_KV * HEAD_DIM, HIDDEN);
  gemm_bf16<<<dim3((N_KV * HEAD_DIM) / 64, S_LEN / 64), blk, 0, stream>>>(
      hsb, WvT, Vraw, S_LEN, N_KV * HEAD_DIM, HIDDEN);

  rope_kernel<<<(S_LEN * (HIDDEN / 2) + 255) / 256, blk, 0, stream>>>(
      Qraw, pos, HIDDEN);
  rope_kernel<<<(S_LEN * (N_KV * HEAD_DIM / 2) + 255) / 256, blk, 0, stream>>>(
      Kraw, pos, N_KV * HEAD_DIM);

  attn_pass1<<<dim3(S_LEN / 32, N_HEADS), blk, 0, stream>>>(
      Qraw, Kraw, Lrow);

  zero_kernel<<<(N_HEADS * S_LEN + 255) / 256, blk, 0, stream>>>(
      cs, N_HEADS * S_LEN);

  attn_pass2<<<dim3(S_LEN / 32, N_HEADS), blk, 0, stream>>>(
      Qraw, Kraw, Vraw, Lrow, cs, attnb);

  topk_mask_kernel<<<N_HEADS, blk, 0, stream>>>(
      cs, out + (size_t)S_LEN * HIDDEN);

  gemm_bf16<<<dim3(HIDDEN / 64, S_LEN / 64), blk, 0, stream>>>(
      attnb, WoT, out, S_LEN, HIDDEN, HIDDEN);
}

// Round 5
// 3636.313 us; speedup vs baseline: 1.9930x; 1.9930x over previous
//
#include <hip/hip_runtime.h>
#include <math.h>

#define S_LEN   2048
#define HIDDEN  4096
#define N_HEADS 32
#define N_KV    8
#define HEAD_DIM 128
#define NCAND   1844      // S - RECENT
#define HEAVY_K 819
#define MASK_LEN 2049     // S + 1

using bf16x8 = __attribute__((ext_vector_type(8))) short;
using f32x4  = __attribute__((ext_vector_type(4))) float;

__device__ inline unsigned short f2bf(float x) {
  unsigned u = __builtin_bit_cast(unsigned, x);
  unsigned r = (u + 0x7FFFu + ((u >> 16) & 1u)) >> 16;
  return (unsigned short)r;
}

// ---------------------------------------------------------------------------
// f32 GEMM, 128x64 tile, BK=32, 8x4 micro-tile.  Mask-critical (Wq/Wk).
// Per-element accumulation is one FMA per strictly-ascending k ->
// bit-identical to the R2 64-tile version (mask provably unchanged).
// NO waves-per-EU cap: ~90 VGPRs needed; the (256,3) cap in R4 caused
// scratch spills and a large regression.
// As k-major [kk][m] stride 132 (reads: 4 addrs/wave, banks {0,8,16,24}+4kk,
// conflict-free); Bs stride 68 (2-way max = free).
// ---------------------------------------------------------------------------
__global__ __launch_bounds__(256) void gemm_f32_128x64(
    const float* __restrict__ A, const float* __restrict__ B,
    float* __restrict__ C, int M, int N, int K)
{
  __shared__ float As[32][132];
  __shared__ float Bs[32][68];
  const int t  = threadIdx.x;
  const int tx = t & 15;       // n micro index (4 cols)
  const int ty = t >> 4;       // m micro index (8 rows)
  const int bm = blockIdx.y << 7;
  const int bn = blockIdx.x << 6;
  const int am  = t >> 3;      // 0..31 (+p*32): A row
  const int ac4 = t & 7;       // float4 index along k
  const int br = t >> 4;       // 0..15 (+16): B k-row
  const int bc = t & 15;       // float4 index along n
  const float4* A4 = (const float4*)A;
  const float4* B4 = (const float4*)B;
  const int K4 = K >> 2;
  const int N4 = N >> 2;

  float acc[8][4];
#pragma unroll
  for (int i = 0; i < 8; i++)
#pragma unroll
    for (int j = 0; j < 4; j++) acc[i][j] = 0.f;

  for (int k0 = 0; k0 < K; k0 += 32) {
    float4 areg[4];
#pragma unroll
    for (int p = 0; p < 4; p++)
      areg[p] = A4[(size_t)(bm + am + p * 32) * K4 + (k0 >> 2) + ac4];
    float4 b0 = B4[(size_t)(k0 + br)      * N4 + (bn >> 2) + bc];
    float4 b1 = B4[(size_t)(k0 + br + 16) * N4 + (bn >> 2) + bc];
    __syncthreads();
#pragma unroll
    for (int p = 0; p < 4; p++) {
      int m = am + p * 32;
      As[ac4 * 4 + 0][m] = areg[p].x;
      As[ac4 * 4 + 1][m] = areg[p].y;
      As[ac4 * 4 + 2][m] = areg[p].z;
      As[ac4 * 4 + 3][m] = areg[p].w;
    }
    *(float4*)&Bs[br][bc * 4]      = b0;
    *(float4*)&Bs[br + 16][bc * 4] = b1;
    __syncthreads();
#pragma unroll
    for (int kk = 0; kk < 32; kk++) {
      float4 a0 = *(const float4*)&As[kk][ty * 8];
      float4 a1 = *(const float4*)&As[kk][ty * 8 + 4];
      float4 bv4 = *(const float4*)&Bs[kk][tx * 4];
      float av[8] = {a0.x, a0.y, a0.z, a0.w, a1.x, a1.y, a1.z, a1.w};
      float bv[4] = {bv4.x, bv4.y, bv4.z, bv4.w};
#pragma unroll
      for (int i = 0; i < 8; i++)
#pragma unroll
        for (int j = 0; j < 4; j++) acc[i][j] += av[i] * bv[j];
    }
  }

#pragma unroll
  for (int i = 0; i < 8; i++) {
    float4 o;
    o.x = acc[i][0]; o.y = acc[i][1]; o.z = acc[i][2]; o.w = acc[i][3];
    *(float4*)&C[(size_t)(bm + ty * 8 + i) * N + bn + tx * 4] = o;
  }
}

// ---------------------------------------------------------------------------
// bf16 MFMA GEMM: C(f32)[M,N] = A(bf16)[M,K] * BT(bf16)[N,K]^T.
// Tile 64x64, BK=32, 4 waves x 2x2 mfma_f32_16x16x32_bf16.
// ---------------------------------------------------------------------------
__global__ __launch_bounds__(256) void gemm_bf16(
    const unsigned short* __restrict__ A, const unsigned short* __restrict__ BT,
    float* __restrict__ C, int M, int N, int K)
{
  __shared__ unsigned short As[64 * 40];
  __shared__ unsigned short Bs[64 * 40];
  const int t    = threadIdx.x;
  const int lane = t & 63;
  const int wave = t >> 6;
  const int mbase = (wave >> 1) * 32;
  const int nbase = (wave & 1) * 32;
  const int bm = blockIdx.y << 6;
  const int bn = blockIdx.x << 6;
  const int srow = t >> 2;
  const int scol = (t & 3) * 8;
  const int l16 = lane & 15;
  const int lk  = (lane >> 4) * 8;

  f32x4 acc00 = {0.f,0.f,0.f,0.f}, acc01 = {0.f,0.f,0.f,0.f};
  f32x4 acc10 = {0.f,0.f,0.f,0.f}, acc11 = {0.f,0.f,0.f,0.f};

  for (int k0 = 0; k0 < K; k0 += 32) {
    float4 av = *(const float4*)(A  + (size_t)(bm + srow) * K + k0 + scol);
    float4 bv = *(const float4*)(BT + (size_t)(bn + srow) * K + k0 + scol);
    __syncthreads();
    *(float4*)(As + srow * 40 + scol) = av;
    *(float4*)(Bs + srow * 40 + scol) = bv;
    __syncthreads();
    bf16x8 a0 = *(const bf16x8*)(As + (mbase + l16)      * 40 + lk);
    bf16x8 a1 = *(const bf16x8*)(As + (mbase + 16 + l16) * 40 + lk);
    bf16x8 b0 = *(const bf16x8*)(Bs + (nbase + l16)      * 40 + lk);
    bf16x8 b1 = *(const bf16x8*)(Bs + (nbase + 16 + l16) * 40 + lk);
    acc00 = __builtin_amdgcn_mfma_f32_16x16x32_bf16(a0, b0, acc00, 0, 0, 0);
    acc01 = __builtin_amdgcn_mfma_f32_16x16x32_bf16(a0, b1, acc01, 0, 0, 0);
    acc10 = __builtin_amdgcn_mfma_f32_16x16x32_bf16(a1, b0, acc10, 0, 0, 0);
    acc11 = __builtin_amdgcn_mfma_f32_16x16x32_bf16(a1, b1, acc11, 0, 0, 0);
  }

  const int rr = (lane >> 4) * 4;
#pragma unroll
  for (int r = 0; r < 4; r++) {
    C[(size_t)(bm + mbase +      rr + r) * N + bn + nbase +      l16] = acc00[r];
    C[(size_t)(bm + mbase +      rr + r) * N + bn + nbase + 16 + l16] = acc01[r];
    C[(size_t)(bm + mbase + 16 + rr + r) * N + bn + nbase +      l16] = acc10[r];
    C[(size_t)(bm + mbase + 16 + rr + r) * N + bn + nbase + 16 + l16] = acc11[r];
  }
}

// ---------------------------------------------------------------------------
// f32 -> bf16 row-major convert.
// ---------------------------------------------------------------------------
__global__ __launch_bounds__(256) void conv_rm(
    const float* __restrict__ src, unsigned short* __restrict__ dst, int n4)
{
  int i = blockIdx.x * 256 + threadIdx.x;
  if (i >= n4) return;
  float4 v = ((const float4*)src)[i];
  ushort4 o;
  o.x = f2bf(v.x); o.y = f2bf(v.y); o.z = f2bf(v.z); o.w = f2bf(v.w);
  ((ushort4*)dst)[i] = o;
}

// ---------------------------------------------------------------------------
// f32 [K][N] -> bf16 [N][K] transpose-convert, 32x32 tiles through LDS.
// ---------------------------------------------------------------------------
__global__ __launch_bounds__(256) void conv_T(
    const float* __restrict__ src, unsigned short* __restrict__ dst,
    int K, int N)
{
  __shared__ float tile[32][33];
  const int tj = blockIdx.x;   // N tile
  const int ti = blockIdx.y;   // K tile
  const int t = threadIdx.x;
  for (int idx = t; idx < 1024; idx += 256) {
    int r = idx >> 5, c = idx & 31;
    tile[r][c] = src[(size_t)(ti * 32 + r) * N + tj * 32 + c];
  }
  __syncthreads();
  for (int idx = t; idx < 1024; idx += 256) {
    int r = idx >> 5, c = idx & 31;
    dst[(size_t)(tj * 32 + r) * K + ti * 32 + c] = f2bf(tile[c][r]);
  }
}

// ---------------------------------------------------------------------------
// In-place RoPE.  inv_freq via f64 pow then rounded to f32 (matches numpy).
// ---------------------------------------------------------------------------
__global__ __launch_bounds__(256) void rope_kernel(
    float* __restrict__ buf, const int* __restrict__ pos_ids, int ncols)
{
  __shared__ float invf_s[64];
  if (threadIdx.x < 64)
    invf_s[threadIdx.x] =
        (float)(1.0 / pow(10000.0, (double)threadIdx.x * (1.0 / 64.0)));
  __syncthreads();

  int i = blockIdx.x * 256 + threadIdx.x;
  int half = ncols >> 1;
  int total = S_LEN * half;
  if (i >= total) return;
  int row = i / half;
  int rem = i - row * half;
  int hh = rem >> 6;
  int d  = rem & 63;
  float p = (float)pos_ids[row];
  float ang = p * invf_s[d];
  float c = cosf(ang);
  float s = sinf(ang);
  float* base = buf + (size_t)row * ncols + hh * HEAD_DIM;
  float x0 = base[d];
  float x1 = base[d + 64];
  base[d]      = x0 * c - x1 * s;
  base[d + 64] = x1 * c + x0 * s;
}

// ---------------------------------------------------------------------------
// Attention pass 1: softmax denominator only (max-free; |s*SCALE| <~ 15).
// ---------------------------------------------------------------------------
__global__ __launch_bounds__(256, 4) void attn_pass1(
    const float* __restrict__ Qr, const float* __restrict__ Kr,
    float* __restrict__ Lrow)
{
  const int qt = gridDim.x - 1 - blockIdx.x;   // big blocks first
  const int h  = blockIdx.y;
  const int q0 = qt << 5;
  const int kvh = h >> 2;
  __shared__ float Qs[32 * 132];
  __shared__ float Ks[32 * 132];
  const int t  = threadIdx.x;
  const int tx = t & 15;
  const int ty = t >> 4;
  const float SCALE = 1.0f / sqrtf(128.0f);

  for (int i = t; i < 32 * 32; i += 256) {
    int r = i >> 5, c4 = i & 31;
    float4 v = ((const float4*)Qr)[(size_t)(q0 + r) * (HIDDEN / 4) + h * 32 + c4];
    *(float4*)(Qs + r * 132 + c4 * 4) = v;
  }

  const int r0 = ty, r1 = ty + 16;
  float l0 = 0.f, l1 = 0.f;

  for (int kt = 0; kt <= qt; kt++) {
    const int k0 = kt << 5;
    __syncthreads();
    for (int i = t; i < 32 * 32; i += 256) {
      int r = i >> 5, c4 = i & 31;
      float4 v = ((const float4*)Kr)[(size_t)(k0 + r) * (N_KV * HEAD_DIM / 4) + kvh * 32 + c4];
      *(float4*)(Ks + r * 132 + c4 * 4) = v;
    }
    __syncthreads();

    float s00 = 0.f, s01 = 0.f, s10 = 0.f, s11 = 0.f;
    const float* qa = Qs + r0 * 132;
    const float* qb = Qs + r1 * 132;
    const float* ka = Ks + tx * 132;
    const float* kb = Ks + (tx + 16) * 132;
#pragma unroll
    for (int kk = 0; kk < 128; kk += 4) {
      float4 a0 = *(const float4*)(qa + kk);
      float4 a1 = *(const float4*)(qb + kk);
      float4 b0 = *(const float4*)(ka + kk);
      float4 b1 = *(const float4*)(kb + kk);
      s00 += a0.x*b0.x + a0.y*b0.y + a0.z*b0.z + a0.w*b0.w;
      s01 += a0.x*b1.x + a0.y*b1.y + a0.z*b1.z + a0.w*b1.w;
      s10 += a1.x*b0.x + a1.y*b0.y + a1.z*b0.z + a1.w*b0.w;
      s11 += a1.x*b1.x + a1.y*b1.y + a1.z*b1.z + a1.w*b1.w;
    }
    l0 += (k0 + tx      <= q0 + r0) ? expf(s00 * SCALE) : 0.f;
    l0 += (k0 + tx + 16 <= q0 + r0) ? expf(s01 * SCALE) : 0.f;
    l1 += (k0 + tx      <= q0 + r1) ? expf(s10 * SCALE) : 0.f;
    l1 += (k0 + tx + 16 <= q0 + r1) ? expf(s11 * SCALE) : 0.f;
  }

#pragma unroll
  for (int off = 1; off < 16; off <<= 1) {
    l0 += __shfl_xor(l0, off);
    l1 += __shfl_xor(l1, off);
  }
  if (tx == 0) {
    Lrow[h * S_LEN + q0 + r0] = l0;
    Lrow[h * S_LEN + q0 + r1] = l1;
  }
}

// ---------------------------------------------------------------------------
// Attention pass 2 — EXACT R2 geometry (best known: 1290 us).
// Qs/Ks stride 132 floats: b128-compatible (16B-aligned rows) AND !=0 mod 32
// banks.  Valid pad strides are {132,136,...}: 128 -> 70M conflicts (R3),
// 130 -> rows lose 16B alignment, compiler drops to narrow LDS reads (R4).
// bf16 output kept (feeds the MFMA Wo GEMM; tolerance path).
// ---------------------------------------------------------------------------
__global__ __launch_bounds__(256, 4) void attn_pass2(
    const float* __restrict__ Qr, const float* __restrict__ Kr,
    const float* __restrict__ Vr, const float* __restrict__ Lrow,
    float* __restrict__ cs, unsigned short* __restrict__ attnb)
{
  const int qt = gridDim.x - 1 - blockIdx.x;   // big blocks first
  const int h  = blockIdx.y;
  const int q0 = qt << 5;
  const int kvh = h >> 2;
  __shared__ float Qs[32 * 132];
  __shared__ float Ks[32 * 132];
  __shared__ float Vs[32 * 128];
  __shared__ float Ps[32 * 33];
  const int t  = threadIdx.x;
  const int tx = t & 15;
  const int ty = t >> 4;
  const float SCALE = 1.0f / sqrtf(128.0f);

  for (int i = t; i < 32 * 32; i += 256) {
    int r = i >> 5, c4 = i & 31;
    float4 v = ((const float4*)Qr)[(size_t)(q0 + r) * (HIDDEN / 4) + h * 32 + c4];
    *(float4*)(Qs + r * 132 + c4 * 4) = v;
  }

  const int r0 = ty, r1 = ty + 16;
  const float iA = 1.0f / Lrow[h * S_LEN + q0 + r0];
  const float iB = 1.0f / Lrow[h * S_LEN + q0 + r1];

  float4 o00 = {0,0,0,0}, o01 = {0,0,0,0}, o10 = {0,0,0,0}, o11 = {0,0,0,0};

  for (int kt = 0; kt <= qt; kt++) {
    const int k0 = kt << 5;
    __syncthreads();
    for (int i = t; i < 32 * 32; i += 256) {
      int r = i >> 5, c4 = i & 31;
      size_t g = (size_t)(k0 + r) * (N_KV * HEAD_DIM / 4) + kvh * 32 + c4;
      *(float4*)(Ks + r * 132 + c4 * 4) = ((const float4*)Kr)[g];
      *(float4*)(Vs + r * 128 + c4 * 4) = ((const float4*)Vr)[g];
    }
    __syncthreads();

    float s00 = 0.f, s01 = 0.f, s10 = 0.f, s11 = 0.f;
    const float* qa = Qs + r0 * 132;
    const float* qb = Qs + r1 * 132;
    const float* ka = Ks + tx * 132;
    const float* kb = Ks + (tx + 16) * 132;
#pragma unroll
    for (int kk = 0; kk < 128; kk += 4) {
      float4 a0 = *(const float4*)(qa + kk);
      float4 a1 = *(const float4*)(qb + kk);
      float4 b0 = *(const float4*)(ka + kk);
      float4 b1 = *(const float4*)(kb + kk);
      s00 += a0.x*b0.x + a0.y*b0.y + a0.z*b0.z + a0.w*b0.w;
      s01 += a0.x*b1.x + a0.y*b1.y + a0.z*b1.z + a0.w*b1.w;
      s10 += a1.x*b0.x + a1.y*b0.y + a1.z*b0.z + a1.w*b0.w;
      s11 += a1.x*b1.x + a1.y*b1.y + a1.z*b1.z + a1.w*b1.w;
    }

    float w00 = (k0 + tx      <= q0 + r0) ? expf(s00 * SCALE) * iA : 0.f;
    float w01 = (k0 + tx + 16 <= q0 + r0) ? expf(s01 * SCALE) * iA : 0.f;
    float w10 = (k0 + tx      <= q0 + r1) ? expf(s10 * SCALE) * iB : 0.f;
    float w11 = (k0 + tx + 16 <= q0 + r1) ? expf(s11 * SCALE) * iB : 0.f;
    Ps[r0 * 33 + tx]      = w00;
    Ps[r0 * 33 + tx + 16] = w01;
    Ps[r1 * 33 + tx]      = w10;
    Ps[r1 * 33 + tx + 16] = w11;
    __syncthreads();

    if (t < 32) {
      float sum = 0.f;
#pragma unroll
      for (int r = 0; r < 32; r++) sum += Ps[r * 33 + t];
      atomicAdd(&cs[h * S_LEN + k0 + t], sum);
    }

#pragma unroll 8
    for (int c = 0; c < 32; c++) {
      float w0 = Ps[r0 * 33 + c];
      float w1 = Ps[r1 * 33 + c];
      float4 va = *(const float4*)(Vs + c * 128 + tx * 4);
      float4 vb = *(const float4*)(Vs + c * 128 + 64 + tx * 4);
      o00.x += w0*va.x; o00.y += w0*va.y; o00.z += w0*va.z; o00.w += w0*va.w;
      o01.x += w0*vb.x; o01.y += w0*vb.y; o01.z += w0*vb.z; o01.w += w0*vb.w;
      o10.x += w1*va.x; o10.y += w1*va.y; o10.z += w1*va.z; o10.w += w1*va.w;
      o11.x += w1*vb.x; o11.y += w1*vb.y; o11.z += w1*vb.z; o11.w += w1*vb.w;
    }
  }

  unsigned short* ob0 = attnb + (size_t)(q0 + r0) * HIDDEN + h * HEAD_DIM;
  unsigned short* ob1 = attnb + (size_t)(q0 + r1) * HIDDEN + h * HEAD_DIM;
  ushort4 p;
  p.x = f2bf(o00.x); p.y = f2bf(o00.y); p.z = f2bf(o00.z); p.w = f2bf(o00.w);
  *(ushort4*)(ob0 + tx * 4) = p;
  p.x = f2bf(o01.x); p.y = f2bf(o01.y); p.z = f2bf(o01.z); p.w = f2bf(o01.w);
  *(ushort4*)(ob0 + 64 + tx * 4) = p;
  p.x = f2bf(o10.x); p.y = f2bf(o10.y); p.z = f2bf(o10.z); p.w = f2bf(o10.w);
  *(ushort4*)(ob1 + tx * 4) = p;
  p.x = f2bf(o11.x); p.y = f2bf(o11.y); p.z = f2bf(o11.z); p.w = f2bf(o11.w);
  *(ushort4*)(ob1 + 64 + tx * 4) = p;
}

// ---------------------------------------------------------------------------
// Exact top-HEAVY_K of the first NCAND scores per head via O(n^2) ranking.
// ---------------------------------------------------------------------------
__global__ __launch_bounds__(256) void topk_mask_kernel(
    const float* __restrict__ cs, float* __restrict__ maskout)
{
  const int h = blockIdx.x;
  __shared__ float sv[NCAND];
  const float* s = cs + h * S_LEN;
  const int t = threadIdx.x;
  for (int i = t; i < NCAND; i += 256) sv[i] = s[i];
  __syncthreads();

  float v[8];
  int cnt[8];
#pragma unroll
  for (int j = 0; j < 8; j++) {
    int i = t + j * 256;
    v[j] = (i < NCAND) ? sv[i] : INFINITY;
    cnt[j] = 0;
  }
  for (int jj = 0; jj < NCAND; jj++) {
    float x = sv[jj];
#pragma unroll
    for (int j = 0; j < 8; j++) {
      int i = t + j * 256;
      cnt[j] += ((x > v[j]) || (x == v[j] && jj < i)) ? 1 : 0;
    }
  }

  float* mrow = maskout + h * MASK_LEN;
  for (int i = t; i < MASK_LEN; i += 256)
    mrow[i] = (i >= NCAND + 1) ? 1.0f : 0.0f;
#pragma unroll
  for (int j = 0; j < 8; j++) {
    int i = t + j * 256;
    if (i < NCAND && cnt[j] < HEAVY_K) mrow[i] = 1.0f;
  }
}

__global__ __launch_bounds__(256) void zero_kernel(float* __restrict__ p, int n)
{
  int i = blockIdx.x * 256 + threadIdx.x;
  if (i < n) p[i] = 0.f;
}

// ---------------------------------------------------------------------------
extern "C" void kernel_launch(void* const* d_in, const int* in_sizes, int n_in,
                              void* d_out, int out_size, void* d_ws, size_t ws_size,
                              hipStream_t stream)
{
  (void)in_sizes; (void)n_in; (void)out_size; (void)ws_size;
  const float* hs = (const float*)d_in[0];
  const int*  pos = (const int*)d_in[1];
  const float* Wq = (const float*)d_in[2];
  const float* Wk = (const float*)d_in[3];
  const float* Wv = (const float*)d_in[4];
  const float* Wo = (const float*)d_in[5];
  float* out = (float*)d_out;

  // workspace layout (~104.5 MB)
  char* w = (char*)d_ws;
  float* Qraw          = (float*)(w);                       // 32 MB
  float* Kraw          = (float*)(w + 33554432);            //  8 MB
  float* Vraw          = (float*)(w + 41943040);            //  8 MB
  float* Lrow          = (float*)(w + 50331648);            //  0.25 MB
  float* cs            = (float*)(w + 50593792);            //  0.25 MB
  unsigned short* WoT  = (unsigned short*)(w + 50855936);   // 32 MB
  unsigned short* WvT  = (unsigned short*)(w + 84410368);   //  8 MB
  unsigned short* hsb  = (unsigned short*)(w + 92798976);   // 16 MB
  unsigned short* attnb = hsb;  // overlay: hsb dead after Wv gemm

  dim3 blk(256);

  conv_rm<<<(S_LEN * HIDDEN / 4 + 255) / 256, blk, 0, stream>>>(
      hs, hsb, S_LEN * HIDDEN / 4);
  conv_T<<<dim3((N_KV * HEAD_DIM) / 32, HIDDEN / 32), blk, 0, stream>>>(
      Wv, WvT, HIDDEN, N_KV * HEAD_DIM);
  conv_T<<<dim3(HIDDEN / 32, HIDDEN / 32), blk, 0, stream>>>(
      Wo, WoT, HIDDEN, HIDDEN);

  gemm_f32_128x64<<<dim3(HIDDEN / 64, S_LEN / 128), blk, 0, stream>>>(
      hs, Wq, Qraw, S_LEN, HIDDEN, HIDDEN);
  gemm_f32_128x64<<<dim3((N_KV * HEAD_DIM) / 64, S_LEN / 128), blk, 0, stream>>>(
      hs, Wk, Kraw, S_LEN, N_KV * HEAD_DIM, HIDDEN);
  gemm_bf16<<<dim3((N_KV * HEAD_DIM) / 64, S_LEN / 64), blk, 0, stream>>>(
      hsb, WvT, Vraw, S_LEN, N_KV * HEAD_DIM, HIDDEN);

  rope_kernel<<<(S_LEN * (HIDDEN / 2) + 255) / 256, blk, 0, stream>>>(
      Qraw, pos, HIDDEN);
  rope_kernel<<<(S_LEN * (N_KV * HEAD_DIM / 2) + 255) / 256, blk, 0, stream>>>(
      Kraw, pos, N_KV * HEAD_DIM);

  attn_pass1<<<dim3(S_LEN / 32, N_HEADS), blk, 0, stream>>>(
      Qraw, Kraw, Lrow);

  zero_kernel<<<(N_HEADS * S_LEN + 255) / 256, blk, 0, stream>>>(
      cs, N_HEADS * S_LEN);

  attn_pass2<<<dim3(S_LEN / 32, N_HEADS), blk, 0, stream>>>(
      Qraw, Kraw, Vraw, Lrow, cs, attnb);

  topk_mask_kernel<<<N_HEADS, blk, 0, stream>>>(
      cs, out + (size_t)S_LEN * HIDDEN);

  gemm_bf16<<<dim3(HIDDEN / 64, S_LEN / 64), blk, 0, stream>>>(
      attnb, WoT, out, S_LEN, HIDDEN, HIDDEN);
}